// Round 1
// baseline (214.659 us; speedup 1.0000x reference)
//
#include <hip/hip_runtime.h>

// UngroundedMicroProgram_3504693313604
// x: (S, 8, 6) fp32. Outputs concatenated fp32:
//   action_probs (2, S, 3)  -- both t-planes identical
//   p_values     (2, 28, S) -- plane r = i*4 + p*2 + k holds |x[s,0,p]-x[s,i+1,p]|
// EXIST_THRESH = 0.8 is a module constant (not an input).

__global__ __launch_bounds__(256) void ump_kernel(
    const float* __restrict__ x,
    const float* __restrict__ action,
    const unsigned char* __restrict__ mask,   // bool array; byte-read works for int8 or int32 layouts
    const float* __restrict__ pred_bounds,
    float* __restrict__ out, int S)
{
    int s = blockIdx.x * blockDim.x + threadIdx.x;
    if (s >= S) return;

    const float* row = x + (size_t)s * 48;

    // agent props x[s,0,0], x[s,0,1] (8B-aligned: row base 192B-aligned)
    float2 a = *(const float2*)(row);

    const float lo0 = pred_bounds[0], hi0 = pred_bounds[1];
    const float lo1 = pred_bounds[2], hi1 = pred_bounds[3];

    float d[14];
    bool enemy_all = true;
    bool any_sat = false;
#pragma unroll
    for (int i = 0; i < 7; ++i) {
        float2 b = *(const float2*)(row + (i + 1) * 6);  // x[s,i+1,0], x[s,i+1,1]
        enemy_all = enemy_all && (b.y > 0.8f);
        float d0 = fabsf(a.x - b.x);
        float d1 = fabsf(a.y - b.y);
        d[2 * i]     = d0;
        d[2 * i + 1] = d1;
        bool s0 = (d0 >= lo0) && (d0 <= hi0) && (d0 >= lo1) && (d0 <= hi1);
        bool s1 = (d1 >= lo0) && (d1 <= hi0) && (d1 >= lo1) && (d1 <= hi1);
        any_sat = any_sat || s0 || s1;
    }

    bool agent_exist = a.x > 0.8f;
    bool m0 = mask[0] != 0;
    bool m1 = mask[1] != 0;
    bool exist     = (m0 == agent_exist) && (m1 == enemy_all);
    bool satisfies = exist && any_sat;

    float an0 = action[0] / (action[0] + 1e-20f);
    float an1 = action[1] / (action[1] + 1e-20f);
    float an2 = action[2] / (action[2] + 1e-20f);
    float v0 = satisfies ? an0 : 0.0f;
    float v1 = satisfies ? an1 : 0.0f;
    float v2 = satisfies ? an2 : 0.0f;

    size_t sl = (size_t)s;
    size_t Sl = (size_t)S;

    // action_probs: (2, S, 3)
    float* ap0 = out + sl * 3;
    ap0[0] = v0; ap0[1] = v1; ap0[2] = v2;
    float* ap1 = out + Sl * 3 + sl * 3;
    ap1[0] = v0; ap1[1] = v1; ap1[2] = v2;

    // p_values: (2, 28, S), plane index = t*28 + i*4 + p*2 + k; value d[2*i+p]
    float* q = out + Sl * 6 + sl;
#pragma unroll
    for (int t = 0; t < 2; ++t) {
#pragma unroll
        for (int i = 0; i < 7; ++i) {
#pragma unroll
            for (int p = 0; p < 2; ++p) {
                float val = d[2 * i + p];
                q[0] = val; q += Sl;   // k = 0
                q[0] = val; q += Sl;   // k = 1
            }
        }
    }
}

extern "C" void kernel_launch(void* const* d_in, const int* in_sizes, int n_in,
                              void* d_out, int out_size, void* d_ws, size_t ws_size,
                              hipStream_t stream) {
    const float*         x           = (const float*)d_in[0];
    const float*         action      = (const float*)d_in[1];
    const unsigned char* mask        = (const unsigned char*)d_in[2];
    const float*         pred_bounds = (const float*)d_in[3];
    float* out = (float*)d_out;

    const int S = in_sizes[0] / 48;  // 524288
    const int block = 256;
    const int grid = (S + block - 1) / block;
    ump_kernel<<<grid, block, 0, stream>>>(x, action, mask, pred_bounds, out, S);
}